// Round 7
// baseline (5820.637 us; speedup 1.0000x reference)
//
#include <hip/hip_runtime.h>
#include <math.h>

#define TSTEPS 1024
#define HID    2048
#define IN_D   128
#define OUT_D  128
#define NWG    256
#define NTHR   512

#define LOG2PI_F 1.8378770664093453f

typedef unsigned long long u64;
typedef unsigned int       u32;

// round-to-nearest-even f32 -> bf16 (low 16 bits)
static __device__ __forceinline__ u32 bf16_rne(float f) {
    u32 u = __float_as_uint(f);
    return (u + 0x7FFFu + ((u >> 16) & 1u)) >> 16;
}
static __device__ __forceinline__ float bf16_f(u32 b) {
    return __uint_as_float(b << 16);
}
// fast transcendentals: v_exp_f32 + v_rcp_f32 (~1 ulp; threshold is 0.21)
static __device__ __forceinline__ float fast_sig(float x) {
    return __builtin_amdgcn_rcpf(1.0f + __expf(-x));
}
static __device__ __forceinline__ float fast_tanh(float x) {
    return 1.0f - 2.0f * __builtin_amdgcn_rcpf(1.0f + __expf(2.0f * x));
}

// ---------------------------------------------------------------------------
// Persistent LSTM rollout. 256 WGs x 512 threads. Wave rg of WG w owns cell
// (8w+rg) COMPLETELY: its 4 gate rows {m*2048 + 8w+rg, m=0..3}, k-slice
// [32*lane, 32*lane+32) per lane -> 128 f32 W_hh in regs/AGPRs per thread.
//
// Per step: poll 4B epoch-tagged packets (bf16 h | tag<<16) -> stage f32 h
// into double-buffered LDS -> ONE syncthreads -> matvec (128 FMA) ->
// 6-round butterfly -> lane 0 does the whole cell update in-wave (fast
// sigmoid/tanh) -> publishes its packet immediately. No second barrier, no
// gsum stage, no serialized cell loop, no fences (relaxed sc1/L3 only).
//
// Safety: exact-match tags. A producer can overwrite tag t (slot parity p)
// with tag t+2 only after observing tag t+1, which is published only after
// the consumer's whole WG passed sync1(t) (i.e. finished reading tag t).
// ldsH double buffer makes the single sync1 sufficient (writes at t+1 hit
// the other buffer; writes at t+2 require passing sync1(t+1)).
// ---------------------------------------------------------------------------
__global__ __launch_bounds__(NTHR, 2)
void lstm_persist(const float* __restrict__ s0,
                  const float* __restrict__ Wih,
                  const float* __restrict__ Whh,
                  const float* __restrict__ bih,
                  const float* __restrict__ bhh,
                  float* __restrict__ hs_out,
                  u32* __restrict__ pkts)      // [2][HID] 4B packets
{
    __shared__ __align__(16) float4 ldsH[2][HID / 4];

    const int tid  = threadIdx.x;
    const int wg   = blockIdx.x;
    const int rg   = tid >> 6;     // wave id 0..7
    const int lane = tid & 63;
    const int cell = wg * 8 + rg;  // this wave's cell

    // ---- weights -> registers ----
    float w[4][32];
    float wih2[4][2];
    float breg[4];
#pragma unroll
    for (int m = 0; m < 4; ++m) {
        const int grow = m * HID + cell;     // gate m, this cell
        const float4* src = (const float4*)(Whh + (size_t)grow * HID + lane * 32);
#pragma unroll
        for (int q = 0; q < 8; ++q) {
            float4 v = src[q];
            w[m][4*q+0] = v.x; w[m][4*q+1] = v.y;
            w[m][4*q+2] = v.z; w[m][4*q+3] = v.w;
        }
        wih2[m][0] = Wih[(size_t)grow * IN_D + 2 * lane];
        wih2[m][1] = Wih[(size_t)grow * IN_D + 2 * lane + 1];
        breg[m]    = bih[grow] + bhh[grow];
    }

    float c = 0.0f;   // cell state (lane 0 of each wave)

    for (int t = 0; t < TSTEPS; ++t) {
        // ---- W_ih @ x_t partial (no h dependency) ----
        const float2 xv = *(const float2*)(s0 + (size_t)t * IN_D + 2 * lane);
        float acc[4];
#pragma unroll
        for (int m = 0; m < 4; ++m)
            acc[m] = wih2[m][0] * xv.x + wih2[m][1] * xv.y;

        // ---- poll own 4 cells' packets of h(t-1); data rides with the tag ----
        if (t > 0) {
            const u32 want = (u32)t & 0xFFFFu;
            const u64* sp = (const u64*)(pkts + (size_t)((t - 1) & 1) * HID + 4 * tid);
            u64 q0, q1;
            for (;;) {
                q0 = __hip_atomic_load(sp,     __ATOMIC_RELAXED, __HIP_MEMORY_SCOPE_AGENT);
                q1 = __hip_atomic_load(sp + 1, __ATOMIC_RELAXED, __HIP_MEMORY_SCOPE_AGENT);
                const u32 t0 = ((u32)(q0 >> 16)) & 0xFFFFu;
                const u32 t1 = (u32)(q0 >> 48);
                const u32 t2 = ((u32)(q1 >> 16)) & 0xFFFFu;
                const u32 t3 = (u32)(q1 >> 48);
                if ((t0 == want) & (t1 == want) & (t2 == want) & (t3 == want)) break;
                __builtin_amdgcn_s_sleep(1);
            }
            float4 hv;
            hv.x = bf16_f((u32)q0 & 0xFFFFu);
            hv.y = bf16_f((u32)(q0 >> 32) & 0xFFFFu);
            hv.z = bf16_f((u32)q1 & 0xFFFFu);
            hv.w = bf16_f((u32)(q1 >> 32) & 0xFFFFu);
            ldsH[(t - 1) & 1][tid ^ ((tid >> 3) & 7)] = hv;   // swizzled
        }
        __syncthreads();   // the ONLY barrier per step

        // ---- recurrent matvec: 4 rows x 32 k per thread ----
        if (t > 0) {
#pragma unroll
            for (int j = 0; j < 8; ++j) {
                const int p = (8 * lane + j) ^ (lane & 7);
                float4 hv = ldsH[(t - 1) & 1][p];
#pragma unroll
                for (int m = 0; m < 4; ++m) {
                    acc[m] += hv.x * w[m][4*j+0];
                    acc[m] += hv.y * w[m][4*j+1];
                    acc[m] += hv.z * w[m][4*j+2];
                    acc[m] += hv.w * w[m][4*j+3];
                }
            }
        }

        // ---- full 64-lane butterfly: complete i,f,g,o sums at lane 0 ----
#pragma unroll
        for (int m = 0; m < 4; ++m) {
            acc[m] += __shfl_xor(acc[m], 1);
            acc[m] += __shfl_xor(acc[m], 2);
            acc[m] += __shfl_xor(acc[m], 4);
            acc[m] += __shfl_xor(acc[m], 8);
            acc[m] += __shfl_xor(acc[m], 16);
            acc[m] += __shfl_xor(acc[m], 32);
        }

        // ---- in-wave cell update + immediate publish (lane 0) ----
        if (lane == 0) {
            const float zi = acc[0] + breg[0];
            const float zf = acc[1] + breg[1];
            const float zg = acc[2] + breg[2];
            const float zo = acc[3] + breg[3];
            const float ig = fast_sig(zi);
            const float fg = fast_sig(zf);
            const float og = fast_sig(zo);
            const float gg = fast_tanh(zg);
            c = fg * c + ig * gg;
            const float h = og * fast_tanh(c);
            const u32 pkt = (((u32)(t + 1) & 0xFFFFu) << 16) | bf16_rne(h);
            __hip_atomic_store(&pkts[(size_t)(t & 1) * HID + cell], pkt,
                               __ATOMIC_RELAXED, __HIP_MEMORY_SCOPE_AGENT);
            hs_out[(size_t)t * HID + cell] = h;   // f32 record for out_head
        }
    }
}

// ---------------------------------------------------------------------------
// Output head: mu/logvar GEMV + sample + logprob. Block = 4 timesteps.
// Off the critical path; hs flushed by kernel-end release.
// ---------------------------------------------------------------------------
__global__ __launch_bounds__(256)
void out_head(const float* __restrict__ eps,
              const float* __restrict__ Wmu,
              const float* __restrict__ bmu,
              const float* __restrict__ Wlv,
              const float* __restrict__ blv,
              const float* __restrict__ hs,
              float* __restrict__ xs,
              float* __restrict__ lp)
{
    __shared__ __align__(16) float hlds[4][HID];
    __shared__ __align__(16) float exch[4][256];

    const int tid = threadIdx.x;
    const int t0  = blockIdx.x * 4;

    {
        const float4* src = (const float4*)(hs + (size_t)t0 * HID);
        float4* dst = (float4*)&hlds[0][0];
#pragma unroll
        for (int i = 0; i < 8; ++i)
            dst[tid + i * 256] = src[tid + i * 256];
    }
    __syncthreads();

    const int  jrow  = tid & 127;
    const bool is_lv = tid >= 128;
    const float* Wrow = (is_lv ? Wlv : Wmu) + (size_t)jrow * HID;
    const float  bias = is_lv ? blv[jrow] : bmu[jrow];

    float acc[4] = {0.f, 0.f, 0.f, 0.f};
    const float4* w4 = (const float4*)Wrow;
#pragma unroll 4
    for (int kq = 0; kq < HID / 4; ++kq) {
        float4 wv = w4[kq];
#pragma unroll
        for (int tt = 0; tt < 4; ++tt) {
            float4 hv = ((const float4*)&hlds[tt][0])[kq];
            acc[tt] += wv.x * hv.x + wv.y * hv.y + wv.z * hv.z + wv.w * hv.w;
        }
    }
#pragma unroll
    for (int tt = 0; tt < 4; ++tt) exch[tt][tid] = acc[tt] + bias;
    __syncthreads();

#pragma unroll
    for (int r = 0; r < 2; ++r) {
        const int item = tid + r * 256;
        const int tt = item >> 7;
        const int jj = item & 127;
        const int t  = t0 + tt;
        const float mu = exch[tt][jj];
        const float lv = exch[tt][128 + jj];
        const float e  = eps[(size_t)t * OUT_D + jj];
        const float sd = expf(0.5f * lv);
        const float x  = mu + sd * e;
        const float d  = (x - mu) / sd;
        const float l  = -0.5f * d * d - 0.5f * lv - 0.5f * LOG2PI_F;
        xs[(size_t)t * OUT_D + jj] = x;
        lp[(size_t)t * OUT_D + jj] = l;
    }
}

// ---------------------------------------------------------------------------
extern "C" void kernel_launch(void* const* d_in, const int* in_sizes, int n_in,
                              void* d_out, int out_size, void* d_ws, size_t ws_size,
                              hipStream_t stream)
{
    (void)in_sizes; (void)n_in; (void)out_size; (void)ws_size;

    const float* s0  = (const float*)d_in[0];
    const float* eps = (const float*)d_in[1];
    const float* Wih = (const float*)d_in[2];
    const float* Whh = (const float*)d_in[3];
    const float* bih = (const float*)d_in[4];
    const float* bhh = (const float*)d_in[5];
    const float* Wmu = (const float*)d_in[6];
    const float* bmu = (const float*)d_in[7];
    const float* Wlv = (const float*)d_in[8];
    const float* blv = (const float*)d_in[9];

    float* out = (float*)d_out;
    float* xs = out;                         // [1024][128]
    float* lp = out + TSTEPS * OUT_D;        // [1024][128]
    float* hs = out + 2 * TSTEPS * OUT_D;    // [1024][2048]

    u32* pkts = (u32*)d_ws;                  // [2][2048] x 4B = 16KB

    // zero tags each launch (tag 0 matches no wanted tag >= 1)
    (void)hipMemsetAsync(d_ws, 0, 2 * HID * sizeof(u32), stream);

    hipLaunchKernelGGL(lstm_persist, dim3(NWG), dim3(NTHR), 0, stream,
                       s0, Wih, Whh, bih, bhh, hs, pkts);

    hipLaunchKernelGGL(out_head, dim3(TSTEPS / 4), dim3(256), 0, stream,
                       eps, Wmu, bmu, Wlv, blv, hs, xs, lp);
}